// Round 6
// baseline (975.329 us; speedup 1.0000x reference)
//
#include <hip/hip_runtime.h>
#include <math.h>

#define B_    1024
#define T_    128
#define D_    64
#define H_    256
#define A_    8

#define NG    8      // batch groups (32 same-XCD blocks each, formed at runtime)
#define NB    32     // blocks per group
#define MB    128    // batch rows per group
#define SL    8      // h-indices owned per block (per layer)
#define FSTR  32     // flag stride in uints (128B -> no line sharing)
#define DYNLDS 36864 // dynamic LDS pad: 48K static + 36K = 86K -> 1 block/CU

typedef __attribute__((ext_vector_type(8))) short short8;
typedef __attribute__((ext_vector_type(4))) float floatx4;

__device__ __forceinline__ short f2bf(float f) {
    union { float f; unsigned u; } x; x.f = f;
    return (short)((x.u + 0x7FFFu + ((x.u >> 16) & 1u)) >> 16);
}
__device__ __forceinline__ float bf2f(short s) {
    union { unsigned u; float f; } x;
    x.u = ((unsigned)(unsigned short)s) << 16;
    return x.f;
}
// fast sigmoid/tanh via v_exp_f32 + v_rcp_f32 (~1e-6 rel err << bf16 lsb)
__device__ __forceinline__ float sigm(float x) {
    return __builtin_amdgcn_rcpf(1.0f + __expf(-x));
}
__device__ __forceinline__ float ftanh(float x) {
    float t = __expf(-2.0f * fabsf(x));
    float r = (1.0f - t) * __builtin_amdgcn_rcpf(1.0f + t);
    return copysignf(r, x);
}

// MFMA C/D frag -> LSTM cell update (layout verified rounds 2-5).
// Chain A holds gates i/f (n-cols 0..7 = i, 8..15 = f), chain B holds g/o.
__device__ __forceinline__ void cell_update(floatx4 aA, floatx4 aB, float* cpair,
                                            short* __restrict__ Hw, size_t rowbase,
                                            int colbase, int hi, int rsel) {
    floatx4 tA, tB;
#pragma unroll
    for (int r = 0; r < 4; ++r) {
        tA[r] = __shfl_xor(aA[r], 8, 64);
        tB[r] = __shfl_xor(aB[r], 8, 64);
    }
#pragma unroll
    for (int rr = 0; rr < 2; ++rr) {
        int r = rsel + rr;
        float gi = hi ? tA[r] : aA[r];
        float gf = hi ? aA[r] : tA[r];
        float gg = hi ? tB[r] : aB[r];
        float go = hi ? aB[r] : tB[r];
        float cn = sigm(gf) * cpair[rr] + sigm(gi) * ftanh(gg);
        float hn = sigm(go) * ftanh(cn);
        cpair[rr] = cn;
        Hw[(rowbase + r) * H_ + colbase] = f2bf(hn);
    }
}

// Grid: 256 blocks x 512 threads (8 waves). With the dynamic-LDS pad each block
// occupies a full CU -> every CU gets exactly 1 block, every XCD exactly 32 ->
// the runtime XCD-local group formation is guaranteed to succeed and the
// fence-free (L2-local) barrier path engages. Without the pad (fallback) the
// formation check decides fast vs safe on its own — correct either way.
__global__ void __launch_bounds__(512, 2)
actor_kernel(const float* __restrict__ state, const float* __restrict__ gamma,
             const float* __restrict__ beta,  const float* __restrict__ Wih0,
             const float* __restrict__ Whh0,  const float* __restrict__ bih0,
             const float* __restrict__ bhh0,  const float* __restrict__ Wih1,
             const float* __restrict__ Whh1,  const float* __restrict__ bih1,
             const float* __restrict__ bhh1,  const float* __restrict__ fcW,
             const float* __restrict__ fcb,   float* __restrict__ out,
             unsigned* __restrict__ flags, unsigned* __restrict__ aux,
             short* __restrict__ Hb0, short* __restrict__ Hb1)
{
    // 48 KB pre-packed weight fragments (round-4 layout; conflict-free b128)
    __shared__ __attribute__((aligned(16))) short sWp[24576];
    __shared__ int sMap[3];   // g, s, fastp
    extern __shared__ char dynPad[];   // unused; forces 1 block/CU when requested
    (void)dynPad;

    const int blk  = blockIdx.x;
    const int tid  = threadIdx.x;
    const int lane = tid & 63;
    const int wave = tid >> 6;

    // ---- runtime XCD-local group formation ----
    if (tid == 0) {
        unsigned xcc;
        asm volatile("s_getreg_b32 %0, hwreg(HW_REG_XCC_ID)" : "=s"(xcc));
        xcc &= 7u;
        unsigned r = atomicAdd(&aux[xcc * 16], 1u);          // rank within XCD
        __hip_atomic_fetch_add(&aux[256], 1u, __ATOMIC_ACQ_REL,
                               __HIP_MEMORY_SCOPE_AGENT);     // grid arrival
        while (__hip_atomic_load(&aux[256], __ATOMIC_RELAXED,
                                 __HIP_MEMORY_SCOPE_AGENT) < (unsigned)gridDim.x)
            __builtin_amdgcn_s_sleep(1);
        __builtin_amdgcn_fence(__ATOMIC_ACQUIRE, "agent");
        int pre = 0, tot = 0; bool ok = true;
        for (int x = 0; x < 8; ++x) {
            int cx = (int)__hip_atomic_load(&aux[x * 16], __ATOMIC_RELAXED,
                                            __HIP_MEMORY_SCOPE_AGENT);
            if (cx & 31) ok = false;
            if (x < (int)xcc) pre += cx >> 5;
            tot += cx >> 5;
        }
        if (tot != NG) ok = false;
        sMap[0] = ok ? (pre + (int)(r >> 5)) : (blk & 7);
        sMap[1] = ok ? (int)(r & 31)         : (blk >> 3);
        sMap[2] = ok ? 1 : 0;
    }
    __syncthreads();
    const int  g     = sMap[0];
    const int  s     = sMap[1];
    const bool fastp = (sMap[2] != 0);
    const int  g128  = g * MB;

    const int q4   = lane >> 4;
    const int l15  = lane & 15;
    const int jj   = l15 & 7;
    const int hi   = l15 >> 3;
    const int rg0  = hi * H_ + s * SL + jj;          // weight row, chain A (i/f)
    const int rg1  = (2 + hi) * H_ + s * SL + jj;    // weight row, chain B (g/o)
    const int mrow = wave * 16 + q4 * 4;             // D-frag base row (M=128)
    const int colbase = s * SL + jj;
    const int rsel = hi * 2;

    // ---------------- prologue ----------------
    float* sXn = (float*)sWp;             // 128 x 65 fp32 (aliases sWp)
    if (tid < MB) {
        const float* xr = state + (size_t)(g128 + tid) * D_;
        float mu = 0.f;
        for (int d = 0; d < D_; ++d) mu += xr[d];
        mu *= (1.0f / D_);
        float var = 0.f;
        for (int d = 0; d < D_; ++d) { float t = xr[d] - mu; var += t * t; }
        var *= (1.0f / D_);
        float is = rsqrtf(var + 1e-5f);
        for (int d = 0; d < D_; ++d)
            sXn[tid * 65 + d] = (xr[d] - mu) * is * gamma[d] + beta[d];
    }
    __syncthreads();

    const float b0v0 = bih0[rg0] + bhh0[rg0];
    const float b0v1 = bih0[rg1] + bhh0[rg1];
    const float b1v0 = bih1[rg0] + bhh1[rg0];
    const float b1v1 = bih1[rg1] + bhh1[rg1];

    floatx4 pre0a, pre0b;                 // xn @ W_ih0.T + b0, MFMA C/D layout
    {
        const float* w0 = Wih0 + (size_t)rg0 * D_;
        const float* w1 = Wih0 + (size_t)rg1 * D_;
#pragma unroll
        for (int r = 0; r < 4; ++r) { pre0a[r] = b0v0; pre0b[r] = b0v1; }
        for (int d = 0; d < D_; ++d) {
            float wa = w0[d], wb = w1[d];
#pragma unroll
            for (int r = 0; r < 4; ++r) {
                float xv = sXn[(mrow + r) * 65 + d];
                pre0a[r] += xv * wa;
                pre0b[r] += xv * wb;
            }
        }
    }
    __syncthreads();   // done with sXn; sWp free for weights

    const int fo = lane >> 3, fk8 = lane & 7;
    float fcw_r[32];
#pragma unroll
    for (int kk = 0; kk < 32; ++kk) fcw_r[kk] = fcW[fo * H_ + fk8 * 32 + kk];
    const float fcb_r = fcb[fo];

    // stage pre-packed weight fragments (fp32 -> bf16)
    for (int idx = tid; idx < 8192; idx += 512) {
        int kt = idx >> 10, rem = idx & 1023;
        int c = rem >> 9, rem2 = rem & 511;
        int ln = rem2 >> 3, j = rem2 & 7;
        int q4_ = ln >> 4, l15_ = ln & 15;
        int n = c * 16 + l15_;
        int r = (n >> 3) * H_ + s * SL + (n & 7);
        int k = kt * 32 + q4_ * 8 + j;
        sWp[idx] = f2bf(Whh0[(size_t)r * H_ + k]);
    }
    for (int idx = tid; idx < 16384; idx += 512) {
        int kt = idx >> 11, rem = idx & 2047;
        int c = rem >> 9, rem2 = rem & 511;
        int ln = rem2 >> 3, j = rem2 & 7;
        int q4_ = ln >> 4, l15_ = ln & 15;
        int n = (c & 1) * 16 + l15_;
        int r = (n >> 3) * H_ + s * SL + (n & 7);
        int k = kt * 32 + q4_ * 8 + j;
        float v = (c >> 1) ? Whh1[(size_t)r * H_ + k] : Wih1[(size_t)r * H_ + k];
        sWp[8192 + idx] = f2bf(v);
    }
    float c0[2] = {0.f, 0.f}, c1[2] = {0.f, 0.f};
    __syncthreads();

    const short* ldsB = sWp + lane * 8;   // one base VGPR; imm offsets everywhere

    // ---------------- phase loop ----------------
    const int BH = B_ * H_;
    for (int ph = 0; ph <= T_ + 1; ++ph) {
        const short* H0r  = Hb0 + ((ph + 1) & 1) * BH;   // h0(ph-1)
        short*       H0w  = Hb0 + (ph & 1) * BH;         // h0(ph)
        const short* H1r2 = Hb1 + (ph & 1) * BH;         // h1(ph-2)
        short*       H1w  = Hb1 + ((ph + 1) & 1) * BH;   // h1(ph-1)

        const bool doL0 = (ph < T_);
        const bool doL1 = (ph >= 1 && ph <= T_);

        if (doL0 || doL1) {
            short8 a0[8], a1[8];
            const short* ap = H0r + (size_t)(g128 + wave * 16 + l15) * H_ + q4 * 8;
#pragma unroll
            for (int kt = 0; kt < 8; ++kt)
                a0[kt] = *(const short8*)(ap + kt * 32);
            if (doL1) {
                const short* cp = H1r2 + (size_t)(g128 + wave * 16 + l15) * H_ + q4 * 8;
#pragma unroll
                for (int kt = 0; kt < 8; ++kt)
                    a1[kt] = *(const short8*)(cp + kt * 32);
            }

            floatx4 l0a = pre0a, l0b = pre0b, l1a, l1b;
#pragma unroll
            for (int r = 0; r < 4; ++r) { l1a[r] = b1v0; l1b[r] = b1v1; }

#pragma unroll
            for (int kt = 0; kt < 8; ++kt) {
                if (doL0) {
                    short8 b0a = *(const short8*)(ldsB + kt * 1024);
                    short8 b0b = *(const short8*)(ldsB + kt * 1024 + 512);
                    l0a = __builtin_amdgcn_mfma_f32_16x16x32_bf16(a0[kt], b0a, l0a, 0, 0, 0);
                    l0b = __builtin_amdgcn_mfma_f32_16x16x32_bf16(a0[kt], b0b, l0b, 0, 0, 0);
                }
                if (doL1) {
                    short8 bia = *(const short8*)(ldsB + 8192 + kt * 2048);
                    short8 bib = *(const short8*)(ldsB + 8192 + kt * 2048 + 512);
                    short8 bha = *(const short8*)(ldsB + 8192 + kt * 2048 + 1024);
                    short8 bhb = *(const short8*)(ldsB + 8192 + kt * 2048 + 1536);
                    l1a = __builtin_amdgcn_mfma_f32_16x16x32_bf16(a0[kt], bia, l1a, 0, 0, 0);
                    l1b = __builtin_amdgcn_mfma_f32_16x16x32_bf16(a0[kt], bib, l1b, 0, 0, 0);
                    l1a = __builtin_amdgcn_mfma_f32_16x16x32_bf16(a1[kt], bha, l1a, 0, 0, 0);
                    l1b = __builtin_amdgcn_mfma_f32_16x16x32_bf16(a1[kt], bhb, l1b, 0, 0, 0);
                }
            }

            size_t rowbase = (size_t)(g128 + mrow);
            if (doL0) cell_update(l0a, l0b, c0, H0w, rowbase, colbase, hi, rsel);
            if (doL1) cell_update(l1a, l1b, c1, H1w, rowbase, colbase, hi, rsel);
        }

        if (ph <= T_) {
            __syncthreads();   // drain h stores (vmcnt(0) before s_barrier)
            if (tid == 0) {
                if (!fastp) __builtin_amdgcn_fence(__ATOMIC_RELEASE, "agent");
                __hip_atomic_store(&flags[(g * NB + s) * FSTR], (unsigned)(ph + 2),
                                   __ATOMIC_RELAXED, __HIP_MEMORY_SCOPE_AGENT);
            }
            // FC for step ph-2 hides under the barrier window
            if (ph >= 2 && wave < 4) {
                int t = ph - 2;
                int b = 4 * s + wave;
                const short8* hp = (const short8*)(H1r2 + (size_t)(g128 + b) * H_ + fk8 * 32);
                float sum = 0.f;
#pragma unroll
                for (int c8 = 0; c8 < 4; ++c8) {
                    short8 hv = hp[c8];
#pragma unroll
                    for (int j = 0; j < 8; ++j)
                        sum += bf2f(hv[j]) * fcw_r[c8 * 8 + j];
                }
                sum += __shfl_down(sum, 4, 8);
                sum += __shfl_down(sum, 2, 8);
                sum += __shfl_down(sum, 1, 8);
                if (fk8 == 0)
                    out[((size_t)(g128 + b) * T_ + t) * A_ + fo] = ftanh(sum + fcb_r);
            }
            if (wave == 7 && lane < NB) {
                while (__hip_atomic_load(&flags[(g * NB + lane) * FSTR],
                                         __ATOMIC_RELAXED, __HIP_MEMORY_SCOPE_AGENT)
                       < (unsigned)(ph + 2))
                    __builtin_amdgcn_s_sleep(1);
            }
            __syncthreads();
            if (fastp) { asm volatile("buffer_inv sc0" ::: "memory"); }
            else       { __builtin_amdgcn_fence(__ATOMIC_ACQUIRE, "agent"); }
        } else if (wave < 4) {
            // ph == T_+1: final FC only
            int t = ph - 2;
            int b = 4 * s + wave;
            const short8* hp = (const short8*)(H1r2 + (size_t)(g128 + b) * H_ + fk8 * 32);
            float sum = 0.f;
#pragma unroll
            for (int c8 = 0; c8 < 4; ++c8) {
                short8 hv = hp[c8];
#pragma unroll
                for (int j = 0; j < 8; ++j)
                    sum += bf2f(hv[j]) * fcw_r[c8 * 8 + j];
            }
            sum += __shfl_down(sum, 4, 8);
            sum += __shfl_down(sum, 2, 8);
            sum += __shfl_down(sum, 1, 8);
            if (fk8 == 0)
                out[((size_t)(g128 + b) * T_ + t) * A_ + fo] = ftanh(sum + fcb_r);
        }
    }
}

extern "C" void kernel_launch(void* const* d_in, const int* in_sizes, int n_in,
                              void* d_out, int out_size, void* d_ws, size_t ws_size,
                              hipStream_t stream)
{
    const float* state = (const float*)d_in[0];
    const float* gamma = (const float*)d_in[1];
    const float* beta  = (const float*)d_in[2];
    const float* Wih0  = (const float*)d_in[3];
    const float* Whh0  = (const float*)d_in[4];
    const float* bih0  = (const float*)d_in[5];
    const float* bhh0  = (const float*)d_in[6];
    const float* Wih1  = (const float*)d_in[7];
    const float* Whh1  = (const float*)d_in[8];
    const float* bih1  = (const float*)d_in[9];
    const float* bhh1  = (const float*)d_in[10];
    const float* fcW   = (const float*)d_in[11];
    const float* fcb   = (const float*)d_in[12];
    float* out = (float*)d_out;

    unsigned* flags = (unsigned*)d_ws;                     // 256 x 128B
    unsigned* aux   = (unsigned*)((char*)d_ws + 32768);    // xcd counters + grid cnt
    short* Hb0 = (short*)((char*)d_ws + 36864);            // 2 x B x H bf16
    short* Hb1 = Hb0 + 2 * B_ * H_;                        // 2 x B x H bf16

    size_t zbytes = 36864 + (size_t)4 * B_ * H_ * sizeof(short);
    hipMemsetAsync(d_ws, 0, zbytes, stream);               // zero flags/aux + h(-1)

    // Host-side (graph-safe, deterministic) check: can a block carry the 86KB
    // total LDS? If yes, the pad forces 1 block/CU -> exact 32 blocks/XCD ->
    // guaranteed fence-free fast path. If not, run without pad (round-5 behavior).
    size_t dynLds = DYNLDS;
    {
        int nb = 0;
        hipError_t qe = hipOccupancyMaxActiveBlocksPerMultiprocessor(
            &nb, (const void*)actor_kernel, 512, DYNLDS);
        if (qe != hipSuccess || nb < 1) { (void)hipGetLastError(); dynLds = 0; }
    }

    void* args[] = { &state, &gamma, &beta, &Wih0, &Whh0, &bih0, &bhh0,
                     &Wih1, &Whh1, &bih1, &bhh1, &fcW, &fcb, &out,
                     &flags, &aux, &Hb0, &Hb1 };
    hipError_t err = hipLaunchCooperativeKernel((const void*)actor_kernel,
                                                dim3(NG * NB), dim3(512),
                                                args, (unsigned)dynLds, stream);
    if (err != hipSuccess) {
        (void)hipGetLastError();
        err = hipLaunchCooperativeKernel((const void*)actor_kernel,
                                         dim3(NG * NB), dim3(512),
                                         args, 0, stream);
        if (err != hipSuccess) {
            (void)hipGetLastError();
            actor_kernel<<<dim3(NG * NB), dim3(512), 0, stream>>>(
                state, gamma, beta, Wih0, Whh0, bih0, bhh0,
                Wih1, Whh1, bih1, bhh1, fcW, fcb, out, flags, aux, Hb0, Hb1);
        }
    }
    (void)in_sizes; (void)n_in; (void)out_size; (void)ws_size;
}

// Round 7
// 972.623 us; speedup vs baseline: 1.0028x; 1.0028x over previous
//
#include <hip/hip_runtime.h>
#include <math.h>

#define B_    1024
#define T_    128
#define D_    64
#define H_    256
#define A_    8

#define NG    8      // batch groups (32 same-XCD blocks each, formed at runtime)
#define NB    32     // blocks per group
#define MB    128    // batch rows per group
#define SL    8      // h-indices owned per block (per layer)
#define FSTR  32     // flag stride in uints (128B -> no line sharing)
#define DYNLDS 36864 // optional dynamic-LDS pad (needs MaxDynamicSharedMemorySize)

typedef __attribute__((ext_vector_type(8))) short short8;
typedef __attribute__((ext_vector_type(4))) float floatx4;

__device__ __forceinline__ short f2bf(float f) {
    union { float f; unsigned u; } x; x.f = f;
    return (short)((x.u + 0x7FFFu + ((x.u >> 16) & 1u)) >> 16);
}
__device__ __forceinline__ float bf2f(short s) {
    union { unsigned u; float f; } x;
    x.u = ((unsigned)(unsigned short)s) << 16;
    return x.f;
}
// fast sigmoid/tanh via v_exp_f32 + v_rcp_f32 (~1e-6 rel err << bf16 lsb)
__device__ __forceinline__ float sigm(float x) {
    return __builtin_amdgcn_rcpf(1.0f + __expf(-x));
}
__device__ __forceinline__ float ftanh(float x) {
    float t = __expf(-2.0f * fabsf(x));
    float r = (1.0f - t) * __builtin_amdgcn_rcpf(1.0f + t);
    return copysignf(r, x);
}

// MFMA C/D frag -> LSTM cell update (layout verified rounds 2-6).
// Chain A holds gates i/f (n-cols 0..7 = i, 8..15 = f), chain B holds g/o.
__device__ __forceinline__ void cell_update(floatx4 aA, floatx4 aB, float* cpair,
                                            short* __restrict__ Hw, size_t rowbase,
                                            int colbase, int hi, int rsel) {
    floatx4 tA, tB;
#pragma unroll
    for (int r = 0; r < 4; ++r) {
        tA[r] = __shfl_xor(aA[r], 8, 64);
        tB[r] = __shfl_xor(aB[r], 8, 64);
    }
#pragma unroll
    for (int rr = 0; rr < 2; ++rr) {
        int r = rsel + rr;
        float gi = hi ? tA[r] : aA[r];
        float gf = hi ? aA[r] : tA[r];
        float gg = hi ? tB[r] : aB[r];
        float go = hi ? aB[r] : tB[r];
        float cn = sigm(gf) * cpair[rr] + sigm(gi) * ftanh(gg);
        float hn = sigm(go) * ftanh(cn);
        cpair[rr] = cn;
        Hw[(rowbase + r) * H_ + colbase] = f2bf(hn);
    }
}

// Grid: 256 blocks x 512 threads (8 waves). The VGPR clobber below forces
// vgpr_count >= 160 -> a CU can host at most 3 waves/SIMD -> a second 8-wave
// block (4 waves/SIMD) cannot co-reside -> capacity == grid == 256 -> every
// XCD gets exactly 32 blocks -> runtime group formation succeeds -> fence-free
// per-XCD-L2 barrier path. Formation check still guards correctness.
__global__ void __launch_bounds__(512, 2)
actor_kernel(const float* __restrict__ state, const float* __restrict__ gamma,
             const float* __restrict__ beta,  const float* __restrict__ Wih0,
             const float* __restrict__ Whh0,  const float* __restrict__ bih0,
             const float* __restrict__ bhh0,  const float* __restrict__ Wih1,
             const float* __restrict__ Whh1,  const float* __restrict__ bih1,
             const float* __restrict__ bhh1,  const float* __restrict__ fcW,
             const float* __restrict__ fcb,   float* __restrict__ out,
             unsigned* __restrict__ flags, unsigned* __restrict__ aux,
             short* __restrict__ Hb0, short* __restrict__ Hb1)
{
    // Occupancy control: mark high VGPRs clobbered -> vgpr_count >= 160 -> 1 block/CU.
    asm volatile("" ::: "v156", "v157", "v158", "v159");

    // 48 KB pre-packed weight fragments (round-4 layout; conflict-free b128)
    __shared__ __attribute__((aligned(16))) short sWp[24576];
    __shared__ int sMap[3];   // g, s, fastp
    extern __shared__ char dynPad[];   // unused; secondary 1-block/CU forcer
    (void)dynPad;

    const int blk  = blockIdx.x;
    const int tid  = threadIdx.x;
    const int lane = tid & 63;
    const int wave = tid >> 6;

    // ---- runtime XCD-local group formation ----
    if (tid == 0) {
        unsigned xcc;
        asm volatile("s_getreg_b32 %0, hwreg(HW_REG_XCC_ID)" : "=s"(xcc));
        xcc &= 7u;
        unsigned r = atomicAdd(&aux[xcc * 16], 1u);          // rank within XCD
        __hip_atomic_fetch_add(&aux[256], 1u, __ATOMIC_ACQ_REL,
                               __HIP_MEMORY_SCOPE_AGENT);     // grid arrival
        while (__hip_atomic_load(&aux[256], __ATOMIC_RELAXED,
                                 __HIP_MEMORY_SCOPE_AGENT) < (unsigned)gridDim.x)
            __builtin_amdgcn_s_sleep(1);
        __builtin_amdgcn_fence(__ATOMIC_ACQUIRE, "agent");
        int pre = 0, tot = 0; bool ok = true;
        for (int x = 0; x < 8; ++x) {
            int cx = (int)__hip_atomic_load(&aux[x * 16], __ATOMIC_RELAXED,
                                            __HIP_MEMORY_SCOPE_AGENT);
            if (cx & 31) ok = false;
            if (x < (int)xcc) pre += cx >> 5;
            tot += cx >> 5;
        }
        if (tot != NG) ok = false;
        sMap[0] = ok ? (pre + (int)(r >> 5)) : (blk & 7);
        sMap[1] = ok ? (int)(r & 31)         : (blk >> 3);
        sMap[2] = ok ? 1 : 0;
    }
    __syncthreads();
    const int  g     = sMap[0];
    const int  s     = sMap[1];
    const bool fastp = (sMap[2] != 0);
    const int  g128  = g * MB;

    const int q4   = lane >> 4;
    const int l15  = lane & 15;
    const int jj   = l15 & 7;
    const int hi   = l15 >> 3;
    const int rg0  = hi * H_ + s * SL + jj;          // weight row, chain A (i/f)
    const int rg1  = (2 + hi) * H_ + s * SL + jj;    // weight row, chain B (g/o)
    const int mrow = wave * 16 + q4 * 4;             // D-frag base row (M=128)
    const int colbase = s * SL + jj;
    const int rsel = hi * 2;

    // ---------------- prologue ----------------
    float* sXn = (float*)sWp;             // 128 x 65 fp32 (aliases sWp)
    if (tid < MB) {
        const float* xr = state + (size_t)(g128 + tid) * D_;
        float mu = 0.f;
        for (int d = 0; d < D_; ++d) mu += xr[d];
        mu *= (1.0f / D_);
        float var = 0.f;
        for (int d = 0; d < D_; ++d) { float t = xr[d] - mu; var += t * t; }
        var *= (1.0f / D_);
        float is = rsqrtf(var + 1e-5f);
        for (int d = 0; d < D_; ++d)
            sXn[tid * 65 + d] = (xr[d] - mu) * is * gamma[d] + beta[d];
    }
    __syncthreads();

    const float b0v0 = bih0[rg0] + bhh0[rg0];
    const float b0v1 = bih0[rg1] + bhh0[rg1];
    const float b1v0 = bih1[rg0] + bhh1[rg0];
    const float b1v1 = bih1[rg1] + bhh1[rg1];

    floatx4 pre0a, pre0b;                 // xn @ W_ih0.T + b0, MFMA C/D layout
    {
        const float* w0 = Wih0 + (size_t)rg0 * D_;
        const float* w1 = Wih0 + (size_t)rg1 * D_;
#pragma unroll
        for (int r = 0; r < 4; ++r) { pre0a[r] = b0v0; pre0b[r] = b0v1; }
        for (int d = 0; d < D_; ++d) {
            float wa = w0[d], wb = w1[d];
#pragma unroll
            for (int r = 0; r < 4; ++r) {
                float xv = sXn[(mrow + r) * 65 + d];
                pre0a[r] += xv * wa;
                pre0b[r] += xv * wb;
            }
        }
    }
    __syncthreads();   // done with sXn; sWp free for weights

    const int fo = lane >> 3, fk8 = lane & 7;
    float fcw_r[32];
#pragma unroll
    for (int kk = 0; kk < 32; ++kk) fcw_r[kk] = fcW[fo * H_ + fk8 * 32 + kk];
    const float fcb_r = fcb[fo];

    // stage pre-packed weight fragments (fp32 -> bf16)
    for (int idx = tid; idx < 8192; idx += 512) {
        int kt = idx >> 10, rem = idx & 1023;
        int c = rem >> 9, rem2 = rem & 511;
        int ln = rem2 >> 3, j = rem2 & 7;
        int q4_ = ln >> 4, l15_ = ln & 15;
        int n = c * 16 + l15_;
        int r = (n >> 3) * H_ + s * SL + (n & 7);
        int k = kt * 32 + q4_ * 8 + j;
        sWp[idx] = f2bf(Whh0[(size_t)r * H_ + k]);
    }
    for (int idx = tid; idx < 16384; idx += 512) {
        int kt = idx >> 11, rem = idx & 2047;
        int c = rem >> 9, rem2 = rem & 511;
        int ln = rem2 >> 3, j = rem2 & 7;
        int q4_ = ln >> 4, l15_ = ln & 15;
        int n = (c & 1) * 16 + l15_;
        int r = (n >> 3) * H_ + s * SL + (n & 7);
        int k = kt * 32 + q4_ * 8 + j;
        float v = (c >> 1) ? Whh1[(size_t)r * H_ + k] : Wih1[(size_t)r * H_ + k];
        sWp[8192 + idx] = f2bf(v);
    }
    float c0[2] = {0.f, 0.f}, c1[2] = {0.f, 0.f};
    __syncthreads();

    const short* ldsB = sWp + lane * 8;   // one base VGPR; imm offsets everywhere

    // ---------------- phase loop ----------------
    const int BH = B_ * H_;
    for (int ph = 0; ph <= T_ + 1; ++ph) {
        const short* H0r  = Hb0 + ((ph + 1) & 1) * BH;   // h0(ph-1)
        short*       H0w  = Hb0 + (ph & 1) * BH;         // h0(ph)
        const short* H1r2 = Hb1 + (ph & 1) * BH;         // h1(ph-2)
        short*       H1w  = Hb1 + ((ph + 1) & 1) * BH;   // h1(ph-1)

        const bool doL0 = (ph < T_);
        const bool doL1 = (ph >= 1 && ph <= T_);

        if (doL0 || doL1) {
            short8 a0[8], a1[8];
            const short* ap = H0r + (size_t)(g128 + wave * 16 + l15) * H_ + q4 * 8;
#pragma unroll
            for (int kt = 0; kt < 8; ++kt)
                a0[kt] = *(const short8*)(ap + kt * 32);
            if (doL1) {
                const short* cp = H1r2 + (size_t)(g128 + wave * 16 + l15) * H_ + q4 * 8;
#pragma unroll
                for (int kt = 0; kt < 8; ++kt)
                    a1[kt] = *(const short8*)(cp + kt * 32);
            }

            floatx4 l0a = pre0a, l0b = pre0b, l1a, l1b;
#pragma unroll
            for (int r = 0; r < 4; ++r) { l1a[r] = b1v0; l1b[r] = b1v1; }

#pragma unroll
            for (int kt = 0; kt < 8; ++kt) {
                if (doL0) {
                    short8 b0a = *(const short8*)(ldsB + kt * 1024);
                    short8 b0b = *(const short8*)(ldsB + kt * 1024 + 512);
                    l0a = __builtin_amdgcn_mfma_f32_16x16x32_bf16(a0[kt], b0a, l0a, 0, 0, 0);
                    l0b = __builtin_amdgcn_mfma_f32_16x16x32_bf16(a0[kt], b0b, l0b, 0, 0, 0);
                }
                if (doL1) {
                    short8 bia = *(const short8*)(ldsB + 8192 + kt * 2048);
                    short8 bib = *(const short8*)(ldsB + 8192 + kt * 2048 + 512);
                    short8 bha = *(const short8*)(ldsB + 8192 + kt * 2048 + 1024);
                    short8 bhb = *(const short8*)(ldsB + 8192 + kt * 2048 + 1536);
                    l1a = __builtin_amdgcn_mfma_f32_16x16x32_bf16(a0[kt], bia, l1a, 0, 0, 0);
                    l1b = __builtin_amdgcn_mfma_f32_16x16x32_bf16(a0[kt], bib, l1b, 0, 0, 0);
                    l1a = __builtin_amdgcn_mfma_f32_16x16x32_bf16(a1[kt], bha, l1a, 0, 0, 0);
                    l1b = __builtin_amdgcn_mfma_f32_16x16x32_bf16(a1[kt], bhb, l1b, 0, 0, 0);
                }
            }

            size_t rowbase = (size_t)(g128 + mrow);
            if (doL0) cell_update(l0a, l0b, c0, H0w, rowbase, colbase, hi, rsel);
            if (doL1) cell_update(l1a, l1b, c1, H1w, rowbase, colbase, hi, rsel);
        }

        if (ph <= T_) {
            __syncthreads();   // drain h stores (vmcnt(0) before s_barrier)
            if (tid == 0) {
                if (!fastp) __builtin_amdgcn_fence(__ATOMIC_RELEASE, "agent");
                __hip_atomic_store(&flags[(g * NB + s) * FSTR], (unsigned)(ph + 2),
                                   __ATOMIC_RELAXED, __HIP_MEMORY_SCOPE_AGENT);
            }
            // FC for step ph-2 hides under the barrier window
            if (ph >= 2 && wave < 4) {
                int t = ph - 2;
                int b = 4 * s + wave;
                const short8* hp = (const short8*)(H1r2 + (size_t)(g128 + b) * H_ + fk8 * 32);
                float sum = 0.f;
#pragma unroll
                for (int c8 = 0; c8 < 4; ++c8) {
                    short8 hv = hp[c8];
#pragma unroll
                    for (int j = 0; j < 8; ++j)
                        sum += bf2f(hv[j]) * fcw_r[c8 * 8 + j];
                }
                sum += __shfl_down(sum, 4, 8);
                sum += __shfl_down(sum, 2, 8);
                sum += __shfl_down(sum, 1, 8);
                if (fk8 == 0)
                    out[((size_t)(g128 + b) * T_ + t) * A_ + fo] = ftanh(sum + fcb_r);
            }
            if (wave == 7 && lane < NB) {
                while (__hip_atomic_load(&flags[(g * NB + lane) * FSTR],
                                         __ATOMIC_RELAXED, __HIP_MEMORY_SCOPE_AGENT)
                       < (unsigned)(ph + 2))
                    __builtin_amdgcn_s_sleep(1);
            }
            __syncthreads();
            if (fastp) { asm volatile("buffer_inv sc0" ::: "memory"); }
            else       { __builtin_amdgcn_fence(__ATOMIC_ACQUIRE, "agent"); }
        } else if (wave < 4) {
            // ph == T_+1: final FC only
            int t = ph - 2;
            int b = 4 * s + wave;
            const short8* hp = (const short8*)(H1r2 + (size_t)(g128 + b) * H_ + fk8 * 32);
            float sum = 0.f;
#pragma unroll
            for (int c8 = 0; c8 < 4; ++c8) {
                short8 hv = hp[c8];
#pragma unroll
                for (int j = 0; j < 8; ++j)
                    sum += bf2f(hv[j]) * fcw_r[c8 * 8 + j];
            }
            sum += __shfl_down(sum, 4, 8);
            sum += __shfl_down(sum, 2, 8);
            sum += __shfl_down(sum, 1, 8);
            if (fk8 == 0)
                out[((size_t)(g128 + b) * T_ + t) * A_ + fo] = ftanh(sum + fcb_r);
        }
    }
}

extern "C" void kernel_launch(void* const* d_in, const int* in_sizes, int n_in,
                              void* d_out, int out_size, void* d_ws, size_t ws_size,
                              hipStream_t stream)
{
    const float* state = (const float*)d_in[0];
    const float* gamma = (const float*)d_in[1];
    const float* beta  = (const float*)d_in[2];
    const float* Wih0  = (const float*)d_in[3];
    const float* Whh0  = (const float*)d_in[4];
    const float* bih0  = (const float*)d_in[5];
    const float* bhh0  = (const float*)d_in[6];
    const float* Wih1  = (const float*)d_in[7];
    const float* Whh1  = (const float*)d_in[8];
    const float* bih1  = (const float*)d_in[9];
    const float* bhh1  = (const float*)d_in[10];
    const float* fcW   = (const float*)d_in[11];
    const float* fcb   = (const float*)d_in[12];
    float* out = (float*)d_out;

    unsigned* flags = (unsigned*)d_ws;                     // 256 x 128B
    unsigned* aux   = (unsigned*)((char*)d_ws + 32768);    // xcd counters + grid cnt
    short* Hb0 = (short*)((char*)d_ws + 36864);            // 2 x B x H bf16
    short* Hb1 = Hb0 + 2 * B_ * H_;                        // 2 x B x H bf16

    size_t zbytes = 36864 + (size_t)4 * B_ * H_ * sizeof(short);
    hipMemsetAsync(d_ws, 0, zbytes, stream);               // zero flags/aux + h(-1)

    // Secondary 1-block/CU forcer: raise the dynamic-LDS cap (round 6 showed the
    // 64KB default rejected the pad), then verify the padded config launches.
    size_t dynLds = DYNLDS;
    {
        (void)hipFuncSetAttribute((const void*)actor_kernel,
                                  hipFuncAttributeMaxDynamicSharedMemorySize, DYNLDS);
        (void)hipGetLastError();
        int nb = 0;
        hipError_t qe = hipOccupancyMaxActiveBlocksPerMultiprocessor(
            &nb, (const void*)actor_kernel, 512, DYNLDS);
        if (qe != hipSuccess || nb < 1) { (void)hipGetLastError(); dynLds = 0; }
    }

    void* args[] = { &state, &gamma, &beta, &Wih0, &Whh0, &bih0, &bhh0,
                     &Wih1, &Whh1, &bih1, &bhh1, &fcW, &fcb, &out,
                     &flags, &aux, &Hb0, &Hb1 };
    hipError_t err = hipLaunchCooperativeKernel((const void*)actor_kernel,
                                                dim3(NG * NB), dim3(512),
                                                args, (unsigned)dynLds, stream);
    if (err != hipSuccess) {
        (void)hipGetLastError();
        err = hipLaunchCooperativeKernel((const void*)actor_kernel,
                                         dim3(NG * NB), dim3(512),
                                         args, 0, stream);
        if (err != hipSuccess) {
            (void)hipGetLastError();
            actor_kernel<<<dim3(NG * NB), dim3(512), 0, stream>>>(
                state, gamma, beta, Wih0, Whh0, bih0, bhh0,
                Wih1, Whh1, bih1, bhh1, fcW, fcb, out, flags, aux, Hb0, Hb1);
        }
    }
    (void)in_sizes; (void)n_in; (void)out_size; (void)ws_size;
}

// Round 9
// 961.597 us; speedup vs baseline: 1.0143x; 1.0115x over previous
//
#include <hip/hip_runtime.h>
#include <math.h>

#define B_    1024
#define T_    128
#define D_    64
#define H_    256
#define A_    8

#define NG    8      // batch groups (32 same-XCD blocks each, formed at runtime)
#define NB    32     // blocks per group
#define MB    128    // batch rows per group
#define SL    8      // h-indices owned per block (per layer)
#define FSTR  32     // flag stride in uints (128B -> no line sharing)

typedef __attribute__((ext_vector_type(8))) short short8;
typedef __attribute__((ext_vector_type(4))) float floatx4;

__device__ __forceinline__ short f2bf(float f) {
    union { float f; unsigned u; } x; x.f = f;
    return (short)((x.u + 0x7FFFu + ((x.u >> 16) & 1u)) >> 16);
}
__device__ __forceinline__ float bf2f(short s) {
    union { unsigned u; float f; } x;
    x.u = ((unsigned)(unsigned short)s) << 16;
    return x.f;
}
// fast sigmoid/tanh via v_exp_f32 + v_rcp_f32 (~1e-6 rel err << bf16 lsb)
__device__ __forceinline__ float sigm(float x) {
    return __builtin_amdgcn_rcpf(1.0f + __expf(-x));
}
__device__ __forceinline__ float ftanh(float x) {
    float t = __expf(-2.0f * fabsf(x));
    float r = (1.0f - t) * __builtin_amdgcn_rcpf(1.0f + t);
    return copysignf(r, x);
}

// MFMA C/D frag -> LSTM cell update (layout verified rounds 2-7).
// Chain A holds gates i/f (n-cols 0..7 = i, 8..15 = f), chain B holds g/o.
__device__ __forceinline__ void cell_update(floatx4 aA, floatx4 aB, float* cpair,
                                            short* __restrict__ Hw, size_t rowbase,
                                            int colbase, int hi, int rsel) {
    floatx4 tA, tB;
#pragma unroll
    for (int r = 0; r < 4; ++r) {
        tA[r] = __shfl_xor(aA[r], 8, 64);
        tB[r] = __shfl_xor(aB[r], 8, 64);
    }
#pragma unroll
    for (int rr = 0; rr < 2; ++rr) {
        int r = rsel + rr;
        float gi = hi ? tA[r] : aA[r];
        float gf = hi ? aA[r] : tA[r];
        float gg = hi ? tB[r] : aB[r];
        float go = hi ? aB[r] : tB[r];
        float cn = sigm(gf) * cpair[rr] + sigm(gi) * ftanh(gg);
        float hn = sigm(go) * ftanh(cn);
        cpair[rr] = cn;
        Hw[(rowbase + r) * H_ + colbase] = f2bf(hn);
    }
}

// Grid: 256 blocks x 512 threads (8 waves). Layer-0 B-fragments live in
// registers (64 VGPRs/wave, live across the whole loop); with
// __launch_bounds__(512) the VGPR cap is 256, so vgpr_count lands >128 ->
// only one 8-wave block fits per CU (VGPR pool) -> capacity == grid == 256 ->
// cooperative co-residency forces a block<->CU bijection -> exactly 32
// blocks/XCD -> runtime group formation succeeds -> fence-free per-XCD-L2
// barrier (round-3 proven protocol). Formation check still guards correctness
// (agent fences under any other placement).
// FC runs at the TOP of the phase (rounds 2-5 proven; no run-ahead race:
// during phase ph other blocks write h1(ph-1) into the other buffer).
__global__ void __launch_bounds__(512)
actor_kernel(const float* __restrict__ state, const float* __restrict__ gamma,
             const float* __restrict__ beta,  const float* __restrict__ Wih0,
             const float* __restrict__ Whh0,  const float* __restrict__ bih0,
             const float* __restrict__ bhh0,  const float* __restrict__ Wih1,
             const float* __restrict__ Whh1,  const float* __restrict__ bih1,
             const float* __restrict__ bhh1,  const float* __restrict__ fcW,
             const float* __restrict__ fcb,   float* __restrict__ out,
             unsigned* __restrict__ flags, unsigned* __restrict__ aux,
             short* __restrict__ Hb0, short* __restrict__ Hb1)
{
    // 48 KB pre-packed weight fragments (round-4 layout; conflict-free b128)
    __shared__ __attribute__((aligned(16))) short sWp[24576];
    __shared__ int sMap[3];   // g, s, fastp

    const int blk  = blockIdx.x;
    const int tid  = threadIdx.x;
    const int lane = tid & 63;
    const int wave = tid >> 6;

    // ---- runtime XCD-local group formation ----
    if (tid == 0) {
        unsigned xcc;
        asm volatile("s_getreg_b32 %0, hwreg(HW_REG_XCC_ID)" : "=s"(xcc));
        xcc &= 7u;
        unsigned r = atomicAdd(&aux[xcc * 16], 1u);          // rank within XCD
        __hip_atomic_fetch_add(&aux[256], 1u, __ATOMIC_ACQ_REL,
                               __HIP_MEMORY_SCOPE_AGENT);     // grid arrival
        while (__hip_atomic_load(&aux[256], __ATOMIC_RELAXED,
                                 __HIP_MEMORY_SCOPE_AGENT) < (unsigned)gridDim.x)
            __builtin_amdgcn_s_sleep(1);
        __builtin_amdgcn_fence(__ATOMIC_ACQUIRE, "agent");
        int pre = 0, tot = 0; bool ok = true;
        for (int x = 0; x < 8; ++x) {
            int cx = (int)__hip_atomic_load(&aux[x * 16], __ATOMIC_RELAXED,
                                            __HIP_MEMORY_SCOPE_AGENT);
            if (cx & 31) ok = false;
            if (x < (int)xcc) pre += cx >> 5;
            tot += cx >> 5;
        }
        if (tot != NG) ok = false;
        sMap[0] = ok ? (pre + (int)(r >> 5)) : (blk & 7);
        sMap[1] = ok ? (int)(r & 31)         : (blk >> 3);
        sMap[2] = ok ? 1 : 0;
    }
    __syncthreads();
    const int  g     = sMap[0];
    const int  s     = sMap[1];
    const bool fastp = (sMap[2] != 0);
    const int  g128  = g * MB;

    const int q4   = lane >> 4;
    const int l15  = lane & 15;
    const int jj   = l15 & 7;
    const int hi   = l15 >> 3;
    const int rg0  = hi * H_ + s * SL + jj;          // weight row, chain A (i/f)
    const int rg1  = (2 + hi) * H_ + s * SL + jj;    // weight row, chain B (g/o)
    const int mrow = wave * 16 + q4 * 4;             // D-frag base row (M=128)
    const int colbase = s * SL + jj;
    const int rsel = hi * 2;

    // ---------------- prologue ----------------
    float* sXn = (float*)sWp;             // 128 x 65 fp32 (aliases sWp)
    if (tid < MB) {
        const float* xr = state + (size_t)(g128 + tid) * D_;
        float mu = 0.f;
        for (int d = 0; d < D_; ++d) mu += xr[d];
        mu *= (1.0f / D_);
        float var = 0.f;
        for (int d = 0; d < D_; ++d) { float t = xr[d] - mu; var += t * t; }
        var *= (1.0f / D_);
        float is = rsqrtf(var + 1e-5f);
        for (int d = 0; d < D_; ++d)
            sXn[tid * 65 + d] = (xr[d] - mu) * is * gamma[d] + beta[d];
    }
    __syncthreads();

    const float b0v0 = bih0[rg0] + bhh0[rg0];
    const float b0v1 = bih0[rg1] + bhh0[rg1];
    const float b1v0 = bih1[rg0] + bhh1[rg0];
    const float b1v1 = bih1[rg1] + bhh1[rg1];

    floatx4 pre0a, pre0b;                 // xn @ W_ih0.T + b0, MFMA C/D layout
    {
        const float* w0 = Wih0 + (size_t)rg0 * D_;
        const float* w1 = Wih0 + (size_t)rg1 * D_;
#pragma unroll
        for (int r = 0; r < 4; ++r) { pre0a[r] = b0v0; pre0b[r] = b0v1; }
        for (int d = 0; d < D_; ++d) {
            float wa = w0[d], wb = w1[d];
#pragma unroll
            for (int r = 0; r < 4; ++r) {
                float xv = sXn[(mrow + r) * 65 + d];
                pre0a[r] += xv * wa;
                pre0b[r] += xv * wb;
            }
        }
    }
    __syncthreads();   // done with sXn; sWp free for weights

    const int fo = lane >> 3, fk8 = lane & 7;
    float fcw_r[32];
#pragma unroll
    for (int kk = 0; kk < 32; ++kk) fcw_r[kk] = fcW[fo * H_ + fk8 * 32 + kk];
    const float fcb_r = fcb[fo];

    // stage pre-packed weight fragments (fp32 -> bf16)
    for (int idx = tid; idx < 8192; idx += 512) {
        int kt = idx >> 10, rem = idx & 1023;
        int c = rem >> 9, rem2 = rem & 511;
        int ln = rem2 >> 3, j = rem2 & 7;
        int q4_ = ln >> 4, l15_ = ln & 15;
        int n = c * 16 + l15_;
        int r = (n >> 3) * H_ + s * SL + (n & 7);
        int k = kt * 32 + q4_ * 8 + j;
        sWp[idx] = f2bf(Whh0[(size_t)r * H_ + k]);
    }
    for (int idx = tid; idx < 16384; idx += 512) {
        int kt = idx >> 11, rem = idx & 2047;
        int c = rem >> 9, rem2 = rem & 511;
        int ln = rem2 >> 3, j = rem2 & 7;
        int q4_ = ln >> 4, l15_ = ln & 15;
        int n = (c & 1) * 16 + l15_;
        int r = (n >> 3) * H_ + s * SL + (n & 7);
        int k = kt * 32 + q4_ * 8 + j;
        float v = (c >> 1) ? Whh1[(size_t)r * H_ + k] : Wih1[(size_t)r * H_ + k];
        sWp[8192 + idx] = f2bf(v);
    }
    float c0[2] = {0.f, 0.f}, c1[2] = {0.f, 0.f};
    __syncthreads();

    // Layer-0 B-fragments -> registers, live for the whole kernel.
    // (64 VGPRs of real pressure: occupancy forcer + kills 1/3 of LDS traffic.)
    short8 bw0[16];
#pragma unroll
    for (int kt = 0; kt < 8; ++kt) {
        bw0[2 * kt]     = *(const short8*)(sWp + kt * 1024 + lane * 8);
        bw0[2 * kt + 1] = *(const short8*)(sWp + kt * 1024 + 512 + lane * 8);
    }
    const short* ldsB = sWp + 8192 + lane * 8;   // L1 frags: imm offsets

    // ---------------- phase loop ----------------
    const int BH = B_ * H_;
    for (int ph = 0; ph <= T_ + 1; ++ph) {
        const short* H0r  = Hb0 + ((ph + 1) & 1) * BH;   // h0(ph-1)
        short*       H0w  = Hb0 + (ph & 1) * BH;         // h0(ph)
        const short* H1r2 = Hb1 + (ph & 1) * BH;         // h1(ph-2)
        short*       H1w  = Hb1 + ((ph + 1) & 1) * BH;   // h1(ph-1)

        const bool doL0 = (ph < T_);
        const bool doL1 = (ph >= 1 && ph <= T_);

        // ---- FC action for step ph-2 (top of phase; rounds 2-5 proven) ----
        if (ph >= 2 && wave < 4) {
            int t = ph - 2;
            int b = 4 * s + wave;
            const short8* hp = (const short8*)(H1r2 + (size_t)(g128 + b) * H_ + fk8 * 32);
            float sum = 0.f;
#pragma unroll
            for (int c8 = 0; c8 < 4; ++c8) {
                short8 hv = hp[c8];
#pragma unroll
                for (int j = 0; j < 8; ++j)
                    sum += bf2f(hv[j]) * fcw_r[c8 * 8 + j];
            }
            sum += __shfl_down(sum, 4, 8);
            sum += __shfl_down(sum, 2, 8);
            sum += __shfl_down(sum, 1, 8);
            if (fk8 == 0)
                out[((size_t)(g128 + b) * T_ + t) * A_ + fo] = ftanh(sum + fcb_r);
        }

        if (doL0 || doL1) {
            short8 a0[8], a1[8];
            const short* ap = H0r + (size_t)(g128 + wave * 16 + l15) * H_ + q4 * 8;
#pragma unroll
            for (int kt = 0; kt < 8; ++kt)
                a0[kt] = *(const short8*)(ap + kt * 32);
            if (doL1) {
                const short* cp = H1r2 + (size_t)(g128 + wave * 16 + l15) * H_ + q4 * 8;
#pragma unroll
                for (int kt = 0; kt < 8; ++kt)
                    a1[kt] = *(const short8*)(cp + kt * 32);
            }

            floatx4 l0a = pre0a, l0b = pre0b, l1a, l1b;
#pragma unroll
            for (int r = 0; r < 4; ++r) { l1a[r] = b1v0; l1b[r] = b1v1; }

#pragma unroll
            for (int kt = 0; kt < 8; ++kt) {
                if (doL0) {
                    l0a = __builtin_amdgcn_mfma_f32_16x16x32_bf16(a0[kt], bw0[2 * kt],     l0a, 0, 0, 0);
                    l0b = __builtin_amdgcn_mfma_f32_16x16x32_bf16(a0[kt], bw0[2 * kt + 1], l0b, 0, 0, 0);
                }
                if (doL1) {
                    short8 bia = *(const short8*)(ldsB + kt * 2048);
                    short8 bib = *(const short8*)(ldsB + kt * 2048 + 512);
                    short8 bha = *(const short8*)(ldsB + kt * 2048 + 1024);
                    short8 bhb = *(const short8*)(ldsB + kt * 2048 + 1536);
                    l1a = __builtin_amdgcn_mfma_f32_16x16x32_bf16(a0[kt], bia, l1a, 0, 0, 0);
                    l1b = __builtin_amdgcn_mfma_f32_16x16x32_bf16(a0[kt], bib, l1b, 0, 0, 0);
                    l1a = __builtin_amdgcn_mfma_f32_16x16x32_bf16(a1[kt], bha, l1a, 0, 0, 0);
                    l1b = __builtin_amdgcn_mfma_f32_16x16x32_bf16(a1[kt], bhb, l1b, 0, 0, 0);
                }
            }

            size_t rowbase = (size_t)(g128 + mrow);
            if (doL0) cell_update(l0a, l0b, c0, H0w, rowbase, colbase, hi, rsel);
            if (doL1) cell_update(l1a, l1b, c1, H1w, rowbase, colbase, hi, rsel);
        }

        // ---- group barrier (round-3 proven protocol) ----
        if (ph <= T_) {
            __syncthreads();   // drain h stores (vmcnt(0) before s_barrier)
            const unsigned val = (unsigned)(ph + 2);
            if (tid == 0) {
                if (!fastp) __builtin_amdgcn_fence(__ATOMIC_RELEASE, "agent");
                __hip_atomic_store(&flags[(g * NB + s) * FSTR], val,
                                   __ATOMIC_RELAXED, __HIP_MEMORY_SCOPE_AGENT);
            }
            if (wave == 7 && lane < NB) {
                while (__hip_atomic_load(&flags[(g * NB + lane) * FSTR],
                                         __ATOMIC_RELAXED, __HIP_MEMORY_SCOPE_AGENT)
                       < val)
                    __builtin_amdgcn_s_sleep(1);
            }
            __syncthreads();
            if (fastp) { asm volatile("buffer_inv sc0" ::: "memory"); }   // L1 inv
            else       { __builtin_amdgcn_fence(__ATOMIC_ACQUIRE, "agent"); }
        }
    }
}

extern "C" void kernel_launch(void* const* d_in, const int* in_sizes, int n_in,
                              void* d_out, int out_size, void* d_ws, size_t ws_size,
                              hipStream_t stream)
{
    const float* state = (const float*)d_in[0];
    const float* gamma = (const float*)d_in[1];
    const float* beta  = (const float*)d_in[2];
    const float* Wih0  = (const float*)d_in[3];
    const float* Whh0  = (const float*)d_in[4];
    const float* bih0  = (const float*)d_in[5];
    const float* bhh0  = (const float*)d_in[6];
    const float* Wih1  = (const float*)d_in[7];
    const float* Whh1  = (const float*)d_in[8];
    const float* bih1  = (const float*)d_in[9];
    const float* bhh1  = (const float*)d_in[10];
    const float* fcW   = (const float*)d_in[11];
    const float* fcb   = (const float*)d_in[12];
    float* out = (float*)d_out;

    unsigned* flags = (unsigned*)d_ws;                     // 256 x 128B
    unsigned* aux   = (unsigned*)((char*)d_ws + 32768);    // xcd counters + grid cnt
    short* Hb0 = (short*)((char*)d_ws + 36864);            // 2 x B x H bf16
    short* Hb1 = Hb0 + 2 * B_ * H_;                        // 2 x B x H bf16

    size_t zbytes = 36864 + (size_t)4 * B_ * H_ * sizeof(short);   // proven size
    hipMemsetAsync(d_ws, 0, zbytes, stream);               // zero flags/aux + h(-1)

    void* args[] = { &state, &gamma, &beta, &Wih0, &Whh0, &bih0, &bhh0,
                     &Wih1, &Whh1, &bih1, &bhh1, &fcW, &fcb, &out,
                     &flags, &aux, &Hb0, &Hb1 };
    hipError_t err = hipLaunchCooperativeKernel((const void*)actor_kernel,
                                                dim3(NG * NB), dim3(512),
                                                args, 0, stream);
    if (err != hipSuccess) {
        (void)hipGetLastError();
        actor_kernel<<<dim3(NG * NB), dim3(512), 0, stream>>>(
            state, gamma, beta, Wih0, Whh0, bih0, bhh0,
            Wih1, Whh1, bih1, bhh1, fcW, fcb, out, flags, aux, Hb0, Hb1);
    }
    (void)in_sizes; (void)n_in; (void)out_size; (void)ws_size;
}